// Round 1
// baseline (249.355 us; speedup 1.0000x reference)
//
#include <hip/hip_runtime.h>
#include <hip/hip_bf16.h>

#define BB 4
#define NN 2048
#define NH 4
#define HDD 16
#define FD 64

typedef __attribute__((ext_vector_type(8))) short bf16x8;
typedef __attribute__((ext_vector_type(4))) float f32x4;

union BW { __hip_bfloat16 b; unsigned short u; };

static __device__ inline unsigned pk2(float a, float b) {
    BW x, y;
    x.b = __float2bfloat16(a);
    y.b = __float2bfloat16(b);
    return (unsigned)x.u | ((unsigned)y.u << 16);
}

static __device__ inline float wsum(float v) {
    v += __shfl_xor(v, 1);  v += __shfl_xor(v, 2);  v += __shfl_xor(v, 4);
    v += __shfl_xor(v, 8);  v += __shfl_xor(v, 16); v += __shfl_xor(v, 32);
    return v;
}

// ---------------- Pass A: qkv = (feat @ Wqc + bqc) @ Wqe + bqe -> Q_ext/K_ext/Vt (bf16)
// Q_ext row (32): [ q*0.25 (16) | bf1[h,n,:] (8) | 0 (8) ]
// K_ext row (32): [ k        (16) | bf2[h,:,n] (8) | 0 (8) ]
// Vt[b][h][d][n] = v
__global__ __launch_bounds__(64) void qkv_kernel(
    const float* __restrict__ feat,
    const float* __restrict__ Wqc, const float* __restrict__ bqc,
    const float* __restrict__ Wqe, const float* __restrict__ bqe,
    const float* __restrict__ bf1, const float* __restrict__ bf2,
    __hip_bfloat16* __restrict__ Qe, __hip_bfloat16* __restrict__ Ke,
    __hip_bfloat16* __restrict__ Vt)
{
    const int bn = blockIdx.x;
    const int b = bn >> 11, n = bn & (NN - 1);
    const int t = threadIdx.x;
    __shared__ float fv[FD];
    __shared__ float cc[24];

    fv[t] = feat[(size_t)bn * FD + t];
    __syncthreads();
    if (t < 24) {
        float a = bqc[t];
        #pragma unroll 8
        for (int d = 0; d < FD; ++d) a += fv[d] * Wqc[d * 24 + t];
        cc[t] = a;
    }
    __syncthreads();

    float v0 = bqe[t], v1 = bqe[t + 64], v2 = bqe[t + 128];
    #pragma unroll
    for (int j = 0; j < 24; ++j) {
        const float c = cc[j];
        v0 += c * Wqe[j * 192 + t];
        v1 += c * Wqe[j * 192 + 64 + t];
        v2 += c * Wqe[j * 192 + 128 + t];
    }
    const int h = t >> 4, hi = t & 15;
    const size_t rowQ = (((size_t)b * NH + h) * NN + n) * 32;
    Qe[rowQ + hi] = __float2bfloat16(v0 * 0.25f);   // fold 1/sqrt(hd)
    Ke[rowQ + hi] = __float2bfloat16(v1);
    Vt[(((size_t)b * NH + h) * HDD + hi) * NN + n] = __float2bfloat16(v2);

    // bias-factor extension + zero padding
    if (t < 32) {
        const int hh = t >> 3, c = t & 7;
        const size_t r = (((size_t)b * NH + hh) * NN + n) * 32;
        Qe[r + 16 + c] = __float2bfloat16(bf1[((size_t)hh * NN + n) * 8 + c]);
        Qe[r + 24 + c] = __float2bfloat16(0.f);
    } else {
        const int hh = (t - 32) >> 3, c = t & 7;
        const size_t r = (((size_t)b * NH + hh) * NN + n) * 32;
        Ke[r + 16 + c] = __float2bfloat16(bf2[((size_t)hh * 8 + c) * NN + n]);
        Ke[r + 24 + c] = __float2bfloat16(0.f);
    }
}

// ---------------- Pass B: fused attention (flash-style, online softmax)
// Block = (b, 16-query tile), 4 waves = 4 heads. S^T = mfma(K_ext, Q_ext).
__global__ __launch_bounds__(256) void attn_kernel(
    const float* __restrict__ fixedg, const float* __restrict__ learng,
    const float* __restrict__ gfus,
    const __hip_bfloat16* __restrict__ Qe, const __hip_bfloat16* __restrict__ Ke,
    const __hip_bfloat16* __restrict__ Vt, float* __restrict__ ctx)
{
    __shared__ float ldsC[2][64 * 20];   // [key local 0..63][q 0..15], stride 20 = conflict-free reads
    __shared__ float ldsO[16][68];       // output transpose buffer

    const int b  = blockIdx.x >> 7;
    const int qb = (blockIdx.x & 127) << 4;
    const int t  = threadIdx.x;
    const int hw = t >> 6;               // head
    const int lane = t & 63;
    const int ql = lane & 15;            // query within tile (MFMA C col)
    const int g  = lane >> 4;            // 16-lane group
    const float fr = 1.f / (1.f + __expf(-gfus[0]));
    const float ofr = 1.f - fr;

    const size_t bhN = ((size_t)b * NH + hw) * NN;
    const bf16x8 qf = *(const bf16x8*)(Qe + (bhN + qb + ql) * 32 + g * 8);
    const __hip_bfloat16* vbase = Vt + (((size_t)b * NH + hw) * HDD + ql) * NN;

    const float* lbase = learng + ((size_t)b * NN + qb) * NN;
    const float* fbase = fixedg + (size_t)qb * NN;
    const int kk = t & 63, q0 = t >> 6;

    float m = -INFINITY, s = 0.f;
    f32x4 acc = {0.f, 0.f, 0.f, 0.f};

#define STAGE(bufi, kt_) { \
    const int col = (kt_) * 64 + kk; \
    for (int qq = q0; qq < 16; qq += 4) { \
        const float lv = lbase[(size_t)qq * NN + col]; \
        const float fvv = fbase[(size_t)qq * NN + col]; \
        ldsC[bufi][kk * 20 + qq] = fr * lv + ofr * fvv; \
    } }

    STAGE(0, 0);
    __syncthreads();

    for (int kt = 0; kt < 32; ++kt) {
        if (kt < 31) STAGE(((kt & 1) ^ 1), kt + 1);
        const int buf = kt & 1;
        #pragma unroll
        for (int hf = 0; hf < 2; ++hf) {
            const int kb = kt * 64 + hf * 32;
            // ----- QK^T (+ low-rank bias via extended dims), S^T tiles
            const bf16x8 k0 = *(const bf16x8*)(Ke + (bhN + kb + ql) * 32 + g * 8);
            const bf16x8 k1 = *(const bf16x8*)(Ke + (bhN + kb + 16 + ql) * 32 + g * 8);
            const f32x4 z = {0.f, 0.f, 0.f, 0.f};
            f32x4 c0 = __builtin_amdgcn_mfma_f32_16x16x32_bf16(k0, qf, z, 0, 0, 0);
            f32x4 c1 = __builtin_amdgcn_mfma_f32_16x16x32_bf16(k1, qf, z, 0, 0, 0);
            // ----- add fused graph from LDS (combined[q][key], lane reg j -> key lk+j)
            const int lk = hf * 32 + 4 * g;
            #pragma unroll
            for (int j = 0; j < 4; ++j) {
                c0[j] += ldsC[buf][(lk + j) * 20 + ql];
                c1[j] += ldsC[buf][(lk + 16 + j) * 20 + ql];
            }
            // ----- online softmax over this 32-key chunk (per query ql)
            float cm = fmaxf(fmaxf(fmaxf(c0[0], c0[1]), fmaxf(c0[2], c0[3])),
                             fmaxf(fmaxf(c1[0], c1[1]), fmaxf(c1[2], c1[3])));
            cm = fmaxf(cm, __shfl_xor(cm, 16));
            cm = fmaxf(cm, __shfl_xor(cm, 32));
            const float mn = fmaxf(m, cm);
            const float scl = __expf(m - mn);
            m = mn;
            float ls = 0.f;
            #pragma unroll
            for (int j = 0; j < 4; ++j) {
                c0[j] = __expf(c0[j] - mn);
                c1[j] = __expf(c1[j] - mn);
                ls += c0[j]; ls += c1[j];
            }
            ls += __shfl_xor(ls, 16);
            ls += __shfl_xor(ls, 32);
            s = s * scl + ls;
            acc[0] *= scl; acc[1] *= scl; acc[2] *= scl; acc[3] *= scl;
            // ----- redistribute P (S^T C-layout) to PV B-fragment layout
            // lane(q,g) holds keys 4g+j (tile0 in w, tile1 in u); target lane(q,g') needs keys 8g'..8g'+7
            unsigned w0 = pk2(c0[0], c0[1]), w1 = pk2(c0[2], c0[3]);
            unsigned u0 = pk2(c1[0], c1[1]), u1 = pk2(c1[2], c1[3]);
            const unsigned w0x = __shfl_xor((int)w0, 16), w1x = __shfl_xor((int)w1, 16);
            const unsigned u0x = __shfl_xor((int)u0, 16), u1x = __shfl_xor((int)u1, 16);
            const bool odd = g & 1;
            const unsigned A0 = odd ? w0x : w0, A1 = odd ? w1x : w1;
            const unsigned A2 = odd ? w0 : w0x, A3 = odd ? w1 : w1x;
            const unsigned B0 = odd ? u0x : u0, B1 = odd ? u1x : u1;
            const unsigned B2 = odd ? u0 : u0x, B3 = odd ? u1 : u1x;
            const unsigned A0s = __shfl_xor((int)A0, 32), A1s = __shfl_xor((int)A1, 32);
            const unsigned A2s = __shfl_xor((int)A2, 32), A3s = __shfl_xor((int)A3, 32);
            const unsigned B0s = __shfl_xor((int)B0, 32), B1s = __shfl_xor((int)B1, 32);
            const unsigned B2s = __shfl_xor((int)B2, 32), B3s = __shfl_xor((int)B3, 32);
            union { unsigned u[4]; bf16x8 v; } pf;
            pf.u[0] = (g == 0) ? A0 : (g == 1) ? A0s : (g == 2) ? B0s : B0;
            pf.u[1] = (g == 0) ? A1 : (g == 1) ? A1s : (g == 2) ? B1s : B1;
            pf.u[2] = (g == 0) ? A2 : (g == 1) ? A2s : (g == 2) ? B2s : B2;
            pf.u[3] = (g == 0) ? A3 : (g == 1) ? A3s : (g == 2) ? B3s : B3;
            // ----- PV: ctx^T += Vt(A) * P^T(B)
            const bf16x8 vf = *(const bf16x8*)(vbase + kb + g * 8);
            acc = __builtin_amdgcn_mfma_f32_16x16x32_bf16(vf, pf.v, acc, 0, 0, 0);
        }
        __syncthreads();
    }

    // normalize + transpose via LDS, coalesced f32 writes
    const float inv = 1.f / s;
    #pragma unroll
    for (int j = 0; j < 4; ++j) ldsO[ql][hw * 16 + 4 * g + j] = acc[j] * inv;
    __syncthreads();
    for (int q2 = q0; q2 < 16; q2 += 4)
        ctx[((size_t)b * NN + qb + q2) * FD + kk] = ldsO[q2][kk];
#undef STAGE
}

// ---------------- Pass C: out = LN((ctx @ Woc + boc) @ Woe + boe + residual)
__global__ __launch_bounds__(256) void out_kernel(
    const float* __restrict__ ctx, const float* __restrict__ feat,
    const float* __restrict__ Woc, const float* __restrict__ boc,
    const float* __restrict__ Woe, const float* __restrict__ boe,
    const float* __restrict__ lng, const float* __restrict__ lnb,
    float* __restrict__ out)
{
    const int node = blockIdx.x * 4 + (threadIdx.x >> 6);
    const int d = threadIdx.x & 63;
    const float cv = ctx[(size_t)node * FD + d];
    float c[8];
    #pragma unroll
    for (int j = 0; j < 8; ++j)
        c[j] = wsum(cv * Woc[d * 8 + j]) + boc[j];
    float o = boe[d];
    #pragma unroll
    for (int j = 0; j < 8; ++j) o += c[j] * Woe[j * 64 + d];
    o += feat[(size_t)node * FD + d];
    const float mu = wsum(o) * (1.f / 64.f);
    const float df = o - mu;
    const float va = wsum(df * df) * (1.f / 64.f);
    out[(size_t)node * FD + d] = df * rsqrtf(va + 1e-5f) * lng[d] + lnb[d];
    if (blockIdx.x == 0 && threadIdx.x == 0)
        out[(size_t)BB * NN * FD] = 4.8828125e-9f;  // 1e-5 * mean(attn) = 1e-5 / N exactly
}

extern "C" void kernel_launch(void* const* d_in, const int* in_sizes, int n_in,
                              void* d_out, int out_size, void* d_ws, size_t ws_size,
                              hipStream_t stream) {
    const float* feat   = (const float*)d_in[0];
    const float* fixedg = (const float*)d_in[1];
    const float* learng = (const float*)d_in[2];
    const float* Wqc = (const float*)d_in[3];
    const float* bqc = (const float*)d_in[4];
    const float* Wqe = (const float*)d_in[5];
    const float* bqe = (const float*)d_in[6];
    const float* Woc = (const float*)d_in[7];
    const float* boc = (const float*)d_in[8];
    const float* Woe = (const float*)d_in[9];
    const float* boe = (const float*)d_in[10];
    const float* bf1 = (const float*)d_in[11];
    const float* bf2 = (const float*)d_in[12];
    const float* gfus = (const float*)d_in[13];
    const float* lng = (const float*)d_in[14];
    const float* lnb = (const float*)d_in[15];

    char* ws = (char*)d_ws;
    __hip_bfloat16* Qe = (__hip_bfloat16*)ws;                       // B*H*N*32 bf16 = 2 MB
    __hip_bfloat16* Ke = Qe + (size_t)BB * NH * NN * 32;            // 2 MB
    __hip_bfloat16* Vt = Ke + (size_t)BB * NH * NN * 32;            // B*H*16*N bf16 = 1 MB
    float* ctx = (float*)(Vt + (size_t)BB * NH * HDD * NN);         // B*N*64 f32 = 2 MB
    float* out = (float*)d_out;

    hipLaunchKernelGGL(qkv_kernel, dim3(BB * NN), dim3(64), 0, stream,
                       feat, Wqc, bqc, Wqe, bqe, bf1, bf2, Qe, Ke, Vt);
    hipLaunchKernelGGL(attn_kernel, dim3(BB * NN / 16), dim3(256), 0, stream,
                       fixedg, learng, gfus, Qe, Ke, Vt, ctx);
    hipLaunchKernelGGL(out_kernel, dim3(BB * NN / 4), dim3(256), 0, stream,
                       ctx, feat, Woc, boc, Woe, boe, lng, lnb, out);
}

// Round 2
// 193.319 us; speedup vs baseline: 1.2899x; 1.2899x over previous
//
#include <hip/hip_runtime.h>
#include <hip/hip_bf16.h>

#define BB 4
#define NN 2048
#define NH 4
#define HDD 16
#define FD 64
#define SPLIT 4
#define KPB (NN / SPLIT)
#define PADC 21
#define L2E 1.44269504088896f

typedef __attribute__((ext_vector_type(8))) short bf16x8;
typedef __attribute__((ext_vector_type(4))) float f32x4;

union BW { __hip_bfloat16 b; unsigned short u; };

static __device__ inline unsigned pk2(float a, float b) {
    BW x, y;
    x.b = __float2bfloat16(a);
    y.b = __float2bfloat16(b);
    return (unsigned)x.u | ((unsigned)y.u << 16);
}

static __device__ inline float wsum(float v) {
    v += __shfl_xor(v, 1);  v += __shfl_xor(v, 2);  v += __shfl_xor(v, 4);
    v += __shfl_xor(v, 8);  v += __shfl_xor(v, 16); v += __shfl_xor(v, 32);
    return v;
}

// ---------------- Pass A: qkv = (feat @ Wqc + bqc) @ Wqe + bqe -> Q_ext/K_ext/Vt (bf16)
// Q_ext row (32): [ q*0.25/ln2 (16) | bf1[h,n,:]/ln2 (8) | 0 (8) ]   (exp2-folded)
// K_ext row (32): [ k           (16) | bf2[h,:,n]     (8) | 0 (8) ]
// Vt[b][h][d][n] = v
__global__ __launch_bounds__(64) void qkv_kernel(
    const float* __restrict__ feat,
    const float* __restrict__ Wqc, const float* __restrict__ bqc,
    const float* __restrict__ Wqe, const float* __restrict__ bqe,
    const float* __restrict__ bf1, const float* __restrict__ bf2,
    __hip_bfloat16* __restrict__ Qe, __hip_bfloat16* __restrict__ Ke,
    __hip_bfloat16* __restrict__ Vt)
{
    const int bn = blockIdx.x;
    const int b = bn >> 11, n = bn & (NN - 1);
    const int t = threadIdx.x;
    __shared__ float fv[FD];
    __shared__ float cc[24];

    fv[t] = feat[(size_t)bn * FD + t];
    __syncthreads();
    if (t < 24) {
        float a = bqc[t];
        #pragma unroll 8
        for (int d = 0; d < FD; ++d) a += fv[d] * Wqc[d * 24 + t];
        cc[t] = a;
    }
    __syncthreads();

    float v0 = bqe[t], v1 = bqe[t + 64], v2 = bqe[t + 128];
    #pragma unroll
    for (int j = 0; j < 24; ++j) {
        const float c = cc[j];
        v0 += c * Wqe[j * 192 + t];
        v1 += c * Wqe[j * 192 + 64 + t];
        v2 += c * Wqe[j * 192 + 128 + t];
    }
    const int h = t >> 4, hi = t & 15;
    const size_t rowQ = (((size_t)b * NH + h) * NN + n) * 32;
    Qe[rowQ + hi] = __float2bfloat16(v0 * (0.25f * L2E));  // fold 1/sqrt(hd) and 1/ln2
    Ke[rowQ + hi] = __float2bfloat16(v1);
    Vt[(((size_t)b * NH + h) * HDD + hi) * NN + n] = __float2bfloat16(v2);

    // bias-factor extension + zero padding
    if (t < 32) {
        const int hh = t >> 3, c = t & 7;
        const size_t r = (((size_t)b * NH + hh) * NN + n) * 32;
        Qe[r + 16 + c] = __float2bfloat16(bf1[((size_t)hh * NN + n) * 8 + c] * L2E);
        Qe[r + 24 + c] = __float2bfloat16(0.f);
    } else {
        const int hh = (t - 32) >> 3, c = t & 7;
        const size_t r = (((size_t)b * NH + hh) * NN + n) * 32;
        Ke[r + 16 + c] = __float2bfloat16(bf2[((size_t)hh * 8 + c) * NN + n]);
        Ke[r + 24 + c] = __float2bfloat16(0.f);
    }
}

// ---------------- Pass B: fused attention, split-K, max-free softmax
// Block = (b, 16-query tile, key-split), 4 waves = 4 heads.
// S^T = mfma(K_ext permuted-rows, Q_ext): lane(ql,g) holds keys 8g..8g+7 of each
// 32-key chunk -> P is already in x32 B-fragment layout -> single PV mfma, no shuffles.
__global__ __launch_bounds__(256, 8) void attn_kernel(
    const float* __restrict__ fixedg, const float* __restrict__ learng,
    const float* __restrict__ gfus,
    const __hip_bfloat16* __restrict__ Qe, const __hip_bfloat16* __restrict__ Ke,
    const __hip_bfloat16* __restrict__ Vt,
    float* __restrict__ pacc, float* __restrict__ psum)
{
    __shared__ float ldsC[2][64 * PADC];   // [key local 0..63][q 0..15], stride 21: conflict-free
    __shared__ float ldsO[16][68];         // output transpose buffer

    const int bid = blockIdx.x;
    const int split = bid & (SPLIT - 1);
    const int qt = (bid >> 2) & 127;
    const int b = bid >> 9;
    const int qb = qt << 4;
    const int kbase = split * KPB;
    const int t = threadIdx.x;
    const int hw = t >> 6;               // head
    const int lane = t & 63;
    const int ql = lane & 15;            // query within tile / V dim row
    const int g  = lane >> 4;            // 16-lane group

    const float sg = 1.f / (1.f + __expf(-gfus[0]));
    const float fre = sg * L2E, ofre = (1.f - sg) * L2E;   // exp2-folded blend

    const size_t bhN = ((size_t)b * NH + hw) * NN;
    const bf16x8 qf = *(const bf16x8*)(Qe + (bhN + qb + ql) * 32 + g * 8);
    const __hip_bfloat16* kptr = Ke + bhN * 32;
    const __hip_bfloat16* vbase = Vt + (((size_t)b * NH + hw) * HDD + ql) * NN;
    const int krow = 8 * (ql >> 2) + (ql & 3);   // permuted key row within chunk

    const float* lbase = learng + ((size_t)b * NN + qb) * NN;
    const float* fbase = fixedg + (size_t)qb * NN;

    float ssum = 0.f;
    f32x4 acc = {0.f, 0.f, 0.f, 0.f};

#define STAGE(bufi, kt_) { \
    const int col = kbase + (kt_) * 64 + lane; \
    for (int qq = hw; qq < 16; qq += 4) \
        ldsC[bufi][lane * PADC + qq] = fre * lbase[(size_t)qq * NN + col] \
                                     + ofre * fbase[(size_t)qq * NN + col]; \
    }

    STAGE(0, 0);
    __syncthreads();

    for (int kt = 0; kt < KPB / 64; ++kt) {
        if (kt < KPB / 64 - 1) STAGE((kt & 1) ^ 1, kt + 1);
        const int buf = kt & 1;
        #pragma unroll
        for (int hf = 0; hf < 2; ++hf) {
            const int kb = kbase + kt * 64 + hf * 32;
            // QK^T (+ low-rank bias via extended dims); key rows permuted so that
            // c0[j] = key kb+8g+j, c1[j] = key kb+8g+4+j
            const bf16x8 k0 = *(const bf16x8*)(kptr + (size_t)(kb + krow) * 32 + g * 8);
            const bf16x8 k1 = *(const bf16x8*)(kptr + (size_t)(kb + 4 + krow) * 32 + g * 8);
            const f32x4 z = {0.f, 0.f, 0.f, 0.f};
            f32x4 c0 = __builtin_amdgcn_mfma_f32_16x16x32_bf16(k0, qf, z, 0, 0, 0);
            f32x4 c1 = __builtin_amdgcn_mfma_f32_16x16x32_bf16(k1, qf, z, 0, 0, 0);
            // add fused graph + exp2 (max-free; scores are bounded small)
            const int lk = hf * 32 + 8 * g;
            #pragma unroll
            for (int j = 0; j < 4; ++j) {
                c0[j] = __builtin_amdgcn_exp2f(c0[j] + ldsC[buf][(lk + j) * PADC + ql]);
                c1[j] = __builtin_amdgcn_exp2f(c1[j] + ldsC[buf][(lk + 4 + j) * PADC + ql]);
                ssum += c0[j] + c1[j];
            }
            // P already in B-fragment layout: keys 8g..8g+7 on this lane
            union { unsigned u[4]; bf16x8 v; } pf;
            pf.u[0] = pk2(c0[0], c0[1]);
            pf.u[1] = pk2(c0[2], c0[3]);
            pf.u[2] = pk2(c1[0], c1[1]);
            pf.u[3] = pk2(c1[2], c1[3]);
            const bf16x8 vf = *(const bf16x8*)(vbase + kb + 8 * g);
            acc = __builtin_amdgcn_mfma_f32_16x16x32_bf16(vf, pf.v, acc, 0, 0, 0);
        }
        __syncthreads();
    }

    // per-query sum of exps (only final reduce needs cross-lane)
    ssum += __shfl_xor(ssum, 16);
    ssum += __shfl_xor(ssum, 32);
    if (g == 0)
        psum[((size_t)(split * BB + b) * NH + hw) * NN + qb + ql] = ssum;

    // unnormalized partial context -> transpose via LDS -> coalesced writes
    #pragma unroll
    for (int j = 0; j < 4; ++j) ldsO[ql][hw * 16 + 4 * g + j] = acc[j];
    __syncthreads();
    for (int q2 = hw; q2 < 16; q2 += 4)
        pacc[((size_t)(split * BB + b) * NN + qb + q2) * FD + lane] = ldsO[q2][lane];
#undef STAGE
}

// ---------------- Pass C: combine splits, out = LN((ctx @ Woc + boc) @ Woe + boe + residual)
__global__ __launch_bounds__(256) void out_kernel(
    const float* __restrict__ pacc, const float* __restrict__ psum,
    const float* __restrict__ feat,
    const float* __restrict__ Woc, const float* __restrict__ boc,
    const float* __restrict__ Woe, const float* __restrict__ boe,
    const float* __restrict__ lng, const float* __restrict__ lnb,
    float* __restrict__ out)
{
    const int node = blockIdx.x * 4 + (threadIdx.x >> 6);
    const int d = threadIdx.x & 63;
    const int b = node >> 11, n = node & (NN - 1);
    const int h = d >> 4;
    float a = 0.f, sh = 0.f;
    #pragma unroll
    for (int sp = 0; sp < SPLIT; ++sp) {
        a  += pacc[((size_t)sp * BB * NN + node) * FD + d];
        sh += psum[((size_t)(sp * BB + b) * NH + h) * NN + n];
    }
    const float cv = a / sh;
    float c[8];
    #pragma unroll
    for (int j = 0; j < 8; ++j)
        c[j] = wsum(cv * Woc[d * 8 + j]) + boc[j];
    float o = boe[d];
    #pragma unroll
    for (int j = 0; j < 8; ++j) o += c[j] * Woe[j * 64 + d];
    o += feat[(size_t)node * FD + d];
    const float mu = wsum(o) * (1.f / 64.f);
    const float df = o - mu;
    const float va = wsum(df * df) * (1.f / 64.f);
    out[(size_t)node * FD + d] = df * rsqrtf(va + 1e-5f) * lng[d] + lnb[d];
    if (blockIdx.x == 0 && threadIdx.x == 0)
        out[(size_t)BB * NN * FD] = 4.8828125e-9f;  // 1e-5 * mean(attn) = 1e-5 / N exactly
}

extern "C" void kernel_launch(void* const* d_in, const int* in_sizes, int n_in,
                              void* d_out, int out_size, void* d_ws, size_t ws_size,
                              hipStream_t stream) {
    const float* feat   = (const float*)d_in[0];
    const float* fixedg = (const float*)d_in[1];
    const float* learng = (const float*)d_in[2];
    const float* Wqc = (const float*)d_in[3];
    const float* bqc = (const float*)d_in[4];
    const float* Wqe = (const float*)d_in[5];
    const float* bqe = (const float*)d_in[6];
    const float* Woc = (const float*)d_in[7];
    const float* boc = (const float*)d_in[8];
    const float* Woe = (const float*)d_in[9];
    const float* boe = (const float*)d_in[10];
    const float* bf1 = (const float*)d_in[11];
    const float* bf2 = (const float*)d_in[12];
    const float* gfus = (const float*)d_in[13];
    const float* lng = (const float*)d_in[14];
    const float* lnb = (const float*)d_in[15];

    char* ws = (char*)d_ws;
    __hip_bfloat16* Qe = (__hip_bfloat16*)ws;                       // 2 MB
    __hip_bfloat16* Ke = Qe + (size_t)BB * NH * NN * 32;            // 2 MB
    __hip_bfloat16* Vt = Ke + (size_t)BB * NH * NN * 32;            // 1 MB
    float* pacc = (float*)(Vt + (size_t)BB * NH * HDD * NN);        // SPLIT*B*N*64 f32 = 8 MB
    float* psum = pacc + (size_t)SPLIT * BB * NN * FD;              // 512 KB
    float* out = (float*)d_out;

    hipLaunchKernelGGL(qkv_kernel, dim3(BB * NN), dim3(64), 0, stream,
                       feat, Wqc, bqc, Wqe, bqe, bf1, bf2, Qe, Ke, Vt);
    hipLaunchKernelGGL(attn_kernel, dim3(BB * (NN / 16) * SPLIT), dim3(256), 0, stream,
                       fixedg, learng, gfus, Qe, Ke, Vt, pacc, psum);
    hipLaunchKernelGGL(out_kernel, dim3(BB * NN / 4), dim3(256), 0, stream,
                       pacc, psum, feat, Woc, boc, Woe, boe, lng, lnb, out);
}